// Round 10
// baseline (392.250 us; speedup 1.0000x reference)
//
#include <hip/hip_runtime.h>
#include <math.h>

#define FDIM 128
#define BKT_BITS 8                 // 256 nodes per bucket
#define BKT_W (1 << BKT_BITS)
#define BIN_CHUNK 12544            // max edges per k_bin block (256-block grid)

typedef short bf16x8 __attribute__((ext_vector_type(8)));
typedef float f32x4 __attribute__((ext_vector_type(4)));
typedef float f32x2 __attribute__((ext_vector_type(2)));

union ABu { bf16x8 v; unsigned int u[4]; };
union F4u { float4 f; float a[4]; };

__device__ inline unsigned int pack_bf16x2(float a, float b) {
  unsigned int ua = __float_as_uint(a);
  unsigned int ub = __float_as_uint(b);
  ua = (ua + 0x7fffu + ((ua >> 16) & 1u)) >> 16;   // RNE
  ub = (ub + 0x7fffu + ((ub >> 16) & 1u)) >> 16;
  return ua | (ub << 16);
}

// fp8 e4m3 (OCP on gfx950) helpers — hardware converts
__device__ inline unsigned char f32_to_fp8(float v) {
  return (unsigned char)(__builtin_amdgcn_cvt_pk_fp8_f32(v, v, 0, false) & 0xff);
}

// ---------------- CSR build: two-level binning ----------------

__global__ __launch_bounds__(256)
void k_bhist(const int* __restrict__ col, int* __restrict__ gbcnt, int nE, int nb) {
  __shared__ int lds[512];
  for (int i = threadIdx.x; i < 512; i += 256) lds[i] = 0;
  __syncthreads();
  int stride = gridDim.x * blockDim.x;
  for (int e = blockIdx.x * blockDim.x + threadIdx.x; e < nE; e += stride)
    atomicAdd(&lds[col[e] >> BKT_BITS], 1);
  __syncthreads();
  for (int b = threadIdx.x; b < nb; b += 256) {
    int c = lds[b];
    if (c) atomicAdd(&gbcnt[b], c);
  }
}

__global__ __launch_bounds__(512)
void k_bscan(const int* __restrict__ gbcnt, int* __restrict__ gboff,
             int* __restrict__ gcur, int nb, int nE) {
  __shared__ int lds[512];
  int t = threadIdx.x;
  lds[t] = (t < nb) ? gbcnt[t] : 0;
  __syncthreads();
  for (int off = 1; off < 512; off <<= 1) {
    int x = (t >= off) ? lds[t - off] : 0;
    __syncthreads();
    lds[t] += x;
    __syncthreads();
  }
  if (t < nb) {
    int excl = (t == 0) ? 0 : lds[t - 1];
    gboff[t] = excl;
    gcur[t] = excl;
  }
  if (t == 0) gboff[nb] = nE;
}

// level-1 scatter: packed (row | col_low<<24), bucket-contiguous.
__global__ __launch_bounds__(256)
void k_bin(const int* __restrict__ row, const int* __restrict__ col,
           int* __restrict__ gcur, int* __restrict__ pairs, int nE, int chunk, int nb) {
  __shared__ int bcnt[512];
  __shared__ int lcur[512];
  __shared__ int ecol[BIN_CHUNK];
  int e0 = blockIdx.x * chunk;
  int e1 = min(e0 + chunk, nE);
  int m = e1 - e0;
  for (int i = threadIdx.x; i < 512; i += 256) bcnt[i] = 0;
  for (int i = threadIdx.x; i < m; i += 256) ecol[i] = col[e0 + i];
  __syncthreads();
  for (int i = threadIdx.x; i < m; i += 256)
    atomicAdd(&bcnt[((unsigned)ecol[i]) >> BKT_BITS], 1);
  __syncthreads();
  for (int b = threadIdx.x; b < nb; b += 256) {
    int c = bcnt[b];
    lcur[b] = c ? atomicAdd(&gcur[b], c) : 0;
  }
  __syncthreads();
  for (int i = threadIdx.x; i < m; i += 256) {
    int c = ecol[i];
    int r = row[e0 + i];
    int p = atomicAdd(&lcur[((unsigned)c) >> BKT_BITS], 1);
    pairs[p] = r | ((c & (BKT_W - 1)) << 24);
  }
}

// fine pass: one block per bucket. cnt/offs/dinv + LDS-cursor scatter of rows.
// srcs is written as BYTE OFFSETS (row*128) for the fp8 gather.
__global__ __launch_bounds__(256)
void k_fine(const int* __restrict__ pairs, const int* __restrict__ gboff,
            int* __restrict__ srcs, int* __restrict__ offs, int* __restrict__ cnt,
            float* __restrict__ dinv, int n) {
  __shared__ int lcnt[256];
  __shared__ int lcur[256];
  int b = blockIdx.x;
  int t = threadIdx.x;
  int ebase = gboff[b];
  int eend = gboff[b + 1];
  lcnt[t] = 0;
  __syncthreads();
  for (int e = ebase + t; e < eend; e += 256)
    atomicAdd(&lcnt[((unsigned)pairs[e]) >> 24], 1);
  __syncthreads();
  int orig = lcnt[t];
  for (int off = 1; off < 256; off <<= 1) {
    int x = (t >= off) ? lcnt[t - off] : 0;
    __syncthreads();
    lcnt[t] += x;
    __syncthreads();
  }
  int excl = lcnt[t] - orig;
  int v = (b << BKT_BITS) + t;
  if (v < n) {
    offs[v] = ebase + excl;
    cnt[v] = orig;
    dinv[v] = rsqrtf((float)(orig + 1));  // +1 self loop
  }
  lcur[t] = ebase + excl;
  __syncthreads();
  for (int e = ebase + t; e < eend; e += 256) {
    int pr = pairs[e];
    int p = atomicAdd(&lcur[((unsigned)pr) >> 24], 1);
    srcs[p] = (pr & 0x00FFFFFF) << 7;   // byte offset of source row
  }
}

// ---------- MFMA GEMM: [n,128] x W[128,128], *dinv[row], fp8 out ----------
// W staged to LDS as W^T bf16, XOR-swizzled (unit ^= col&15 -> 2-way = free).
#define STAGE_WT()                                                          \
  {                                                                         \
    int c = threadIdx.x & 127;                                              \
    for (int kp = (threadIdx.x >> 7); kp < 64; kp += 2) {                   \
      float w0 = W[(kp * 2) * 128 + c];                                     \
      float w1 = W[(kp * 2 + 1) * 128 + c];                                 \
      int unit = kp >> 2, dw = kp & 3;                                      \
      wlds[c * 64 + ((unit ^ (c & 15)) << 2) + dw] = pack_bf16x2(w0, w1);   \
    }                                                                       \
  }                                                                         \
  __syncthreads();

#define GEMM_BODY()                                                         \
  int l = threadIdx.x & 63;                                                 \
  int grp = l >> 4, c15 = l & 15;                                           \
  int rbase = blockIdx.x * 64 + (threadIdx.x >> 6) * 16;                    \
  F4u dv;                                                                   \
  dv.f = *(const float4*)(dinv + rbase + grp * 4);                          \
  f32x4 acc[8];                                                             \
  _Pragma("unroll")                                                         \
  for (int nt = 0; nt < 8; ++nt) acc[nt] = (f32x4){0.f, 0.f, 0.f, 0.f};    \
  _Pragma("unroll")                                                         \
  for (int nt = 0; nt < 8; ++nt) {                                          \
    _Pragma("unroll")                                                       \
    for (int ks = 0; ks < 4; ++ks) {                                        \
      ABu b;                                                                \
      b.v = *(const bf16x8*)&wlds[(nt * 16 + c15) * 64 +                    \
                                  ((((ks << 2) + grp) ^ c15) << 2)];        \
      acc[nt] = __builtin_amdgcn_mfma_f32_16x16x32_bf16(a[ks].v, b.v,       \
                                                        acc[nt], 0, 0, 0);  \
    }                                                                       \
  }                                                                         \
  _Pragma("unroll")                                                         \
  for (int nt = 0; nt < 8; ++nt) {                                          \
    _Pragma("unroll")                                                       \
    for (int i = 0; i < 4; ++i) {                                           \
      int r = rbase + grp * 4 + i;                                          \
      if (r < n) {                                                          \
        float v = acc[nt][i] * dv.a[i];                                     \
        out[(size_t)r * 128 + nt * 16 + c15] = f32_to_fp8(v);               \
      }                                                                     \
    }                                                                       \
  }

__global__ __launch_bounds__(256)
void k_gemm_mfma_f(const float* __restrict__ in, const float* __restrict__ W,
                   const float* __restrict__ dinv, unsigned char* __restrict__ out,
                   int n) {
  __shared__ unsigned int wlds[128 * 64];
  STAGE_WT();
  {
    int l0 = threadIdx.x & 63;
    int row = blockIdx.x * 64 + (threadIdx.x >> 6) * 16 + (l0 & 15);
    int rowc = min(row, n - 1);
    int grp0 = l0 >> 4;
    const float4* xr = (const float4*)(in + (size_t)rowc * 128);
    ABu a[4];
#pragma unroll
    for (int ks = 0; ks < 4; ++ks) {
      float4 f0 = xr[ks * 8 + grp0 * 2];
      float4 f1 = xr[ks * 8 + grp0 * 2 + 1];
      a[ks].u[0] = pack_bf16x2(f0.x, f0.y);
      a[ks].u[1] = pack_bf16x2(f0.z, f0.w);
      a[ks].u[2] = pack_bf16x2(f1.x, f1.y);
      a[ks].u[3] = pack_bf16x2(f1.z, f1.w);
    }
    GEMM_BODY();
  }
}

__global__ __launch_bounds__(256)
void k_gemm_mfma_b(const unsigned int* __restrict__ in, const float* __restrict__ W,
                   const float* __restrict__ dinv, unsigned char* __restrict__ out,
                   int n) {
  __shared__ unsigned int wlds[128 * 64];
  STAGE_WT();
  {
    int l0 = threadIdx.x & 63;
    int row = blockIdx.x * 64 + (threadIdx.x >> 6) * 16 + (l0 & 15);
    int rowc = min(row, n - 1);
    int grp0 = l0 >> 4;
    const unsigned int* hr = in + (size_t)rowc * 64;
    ABu a[4];
#pragma unroll
    for (int ks = 0; ks < 4; ++ks)
      a[ks].v = *(const bf16x8*)&hr[ks * 16 + grp0 * 4];
    GEMM_BODY();
  }
}

// ------ gather core: wave/node, dword/lane, 2 rows/iter, direct offset loads ------
// srcs holds byte offsets; half-wave hf loads its own row offset (same-address
// broadcast within the half-wave), gather uses 32-bit voffset vs SGPR base.
__device__ inline float4 agg_core(const unsigned char* __restrict__ s8,
                                  const int* __restrict__ offs,
                                  const int* __restrict__ cnt,
                                  const int* __restrict__ srcs,
                                  int v, int lane) {
  int cl = lane & 31;
  int hf = lane >> 5;
  int co = cl * 4;               // byte offset of this lane's 4 fp8 cols
  float4 acc = make_float4(0.f, 0.f, 0.f, 0.f);
  if (lane < 32) {  // self contribution counted once
    unsigned int q = *(const unsigned int*)(s8 + (unsigned)(v * 128 + co));
    f32x2 lo = __builtin_amdgcn_cvt_pk_f32_fp8((int)q, false);
    f32x2 hi = __builtin_amdgcn_cvt_pk_f32_fp8((int)q, true);
    acc = make_float4(lo[0], lo[1], hi[0], hi[1]);
  }
  int m = cnt[v];
  const int* sp = srcs + offs[v];
  int it = 0;
  for (; it + 15 < m; it += 16) {
    int o0 = sp[it + hf];
    int o1 = sp[it + 2 + hf];
    int o2 = sp[it + 4 + hf];
    int o3 = sp[it + 6 + hf];
    int o4 = sp[it + 8 + hf];
    int o5 = sp[it + 10 + hf];
    int o6 = sp[it + 12 + hf];
    int o7 = sp[it + 14 + hf];
    unsigned int q0 = *(const unsigned int*)(s8 + (unsigned)(o0 + co));
    unsigned int q1 = *(const unsigned int*)(s8 + (unsigned)(o1 + co));
    unsigned int q2 = *(const unsigned int*)(s8 + (unsigned)(o2 + co));
    unsigned int q3 = *(const unsigned int*)(s8 + (unsigned)(o3 + co));
    unsigned int q4 = *(const unsigned int*)(s8 + (unsigned)(o4 + co));
    unsigned int q5 = *(const unsigned int*)(s8 + (unsigned)(o5 + co));
    unsigned int q6 = *(const unsigned int*)(s8 + (unsigned)(o6 + co));
    unsigned int q7 = *(const unsigned int*)(s8 + (unsigned)(o7 + co));
    f32x2 l0 = __builtin_amdgcn_cvt_pk_f32_fp8((int)q0, false);
    f32x2 h0 = __builtin_amdgcn_cvt_pk_f32_fp8((int)q0, true);
    f32x2 l1 = __builtin_amdgcn_cvt_pk_f32_fp8((int)q1, false);
    f32x2 h1 = __builtin_amdgcn_cvt_pk_f32_fp8((int)q1, true);
    f32x2 l2 = __builtin_amdgcn_cvt_pk_f32_fp8((int)q2, false);
    f32x2 h2 = __builtin_amdgcn_cvt_pk_f32_fp8((int)q2, true);
    f32x2 l3 = __builtin_amdgcn_cvt_pk_f32_fp8((int)q3, false);
    f32x2 h3 = __builtin_amdgcn_cvt_pk_f32_fp8((int)q3, true);
    f32x2 l4 = __builtin_amdgcn_cvt_pk_f32_fp8((int)q4, false);
    f32x2 h4 = __builtin_amdgcn_cvt_pk_f32_fp8((int)q4, true);
    f32x2 l5 = __builtin_amdgcn_cvt_pk_f32_fp8((int)q5, false);
    f32x2 h5 = __builtin_amdgcn_cvt_pk_f32_fp8((int)q5, true);
    f32x2 l6 = __builtin_amdgcn_cvt_pk_f32_fp8((int)q6, false);
    f32x2 h6 = __builtin_amdgcn_cvt_pk_f32_fp8((int)q6, true);
    f32x2 l7 = __builtin_amdgcn_cvt_pk_f32_fp8((int)q7, false);
    f32x2 h7 = __builtin_amdgcn_cvt_pk_f32_fp8((int)q7, true);
    acc.x += ((l0[0] + l1[0]) + (l2[0] + l3[0])) + ((l4[0] + l5[0]) + (l6[0] + l7[0]));
    acc.y += ((l0[1] + l1[1]) + (l2[1] + l3[1])) + ((l4[1] + l5[1]) + (l6[1] + l7[1]));
    acc.z += ((h0[0] + h1[0]) + (h2[0] + h3[0])) + ((h4[0] + h5[0]) + (h6[0] + h7[0]));
    acc.w += ((h0[1] + h1[1]) + (h2[1] + h3[1])) + ((h4[1] + h5[1]) + (h6[1] + h7[1]));
  }
  for (; it + 1 < m; it += 2) {
    int o = sp[it + hf];
    unsigned int q = *(const unsigned int*)(s8 + (unsigned)(o + co));
    f32x2 lo = __builtin_amdgcn_cvt_pk_f32_fp8((int)q, false);
    f32x2 hi = __builtin_amdgcn_cvt_pk_f32_fp8((int)q, true);
    acc.x += lo[0]; acc.y += lo[1]; acc.z += hi[0]; acc.w += hi[1];
  }
  if (it < m && lane < 32) {  // odd tail: low half only
    int o = sp[it];
    unsigned int q = *(const unsigned int*)(s8 + (unsigned)(o + co));
    f32x2 lo = __builtin_amdgcn_cvt_pk_f32_fp8((int)q, false);
    f32x2 hi = __builtin_amdgcn_cvt_pk_f32_fp8((int)q, true);
    acc.x += lo[0]; acc.y += lo[1]; acc.z += hi[0]; acc.w += hi[1];
  }
  // combine the two half-wave partials
  acc.x += __shfl_xor(acc.x, 32, 64);
  acc.y += __shfl_xor(acc.y, 32, 64);
  acc.z += __shfl_xor(acc.z, 32, 64);
  acc.w += __shfl_xor(acc.w, 32, 64);
  return acc;
}

// layer-1 aggregate: h = relu(dinv*(...)+b), stored bf16 (coalesced reader)
__global__ __launch_bounds__(256)
void k_agg_mid(const unsigned char* __restrict__ s8, const int* __restrict__ offs,
               const int* __restrict__ cnt, const int* __restrict__ srcs,
               const float* __restrict__ dinv, const float* __restrict__ bias,
               unsigned int* __restrict__ hb, int n) {
  int v = (int)(((size_t)blockIdx.x * blockDim.x + threadIdx.x) >> 6);
  if (v >= n) return;
  int lane = threadIdx.x & 63;
  float4 acc = agg_core(s8, offs, cnt, srcs, v, lane);
  if (lane < 32) {
    int cl = lane;
    float d = dinv[v];
    float4 bb = ((const float4*)bias)[cl];
    float r0 = fmaxf(acc.x * d + bb.x, 0.0f);
    float r1 = fmaxf(acc.y * d + bb.y, 0.0f);
    float r2 = fmaxf(acc.z * d + bb.z, 0.0f);
    float r3 = fmaxf(acc.w * d + bb.w, 0.0f);
    uint2 pk;
    pk.x = pack_bf16x2(r0, r1);
    pk.y = pack_bf16x2(r2, r3);
    ((uint2*)hb)[(size_t)v * 32 + cl] = pk;
  }
}

// layer-2 aggregate fused with head: out = sigmoid(relu(...)@Wl + bl)
__global__ __launch_bounds__(256)
void k_agg_head(const unsigned char* __restrict__ s8, const int* __restrict__ offs,
                const int* __restrict__ cnt, const int* __restrict__ srcs,
                const float* __restrict__ dinv, const float* __restrict__ bias,
                const float* __restrict__ Wl, const float* __restrict__ bl,
                float* __restrict__ out, int n) {
  int v = (int)(((size_t)blockIdx.x * blockDim.x + threadIdx.x) >> 6);
  if (v >= n) return;
  int lane = threadIdx.x & 63;
  float4 acc = agg_core(s8, offs, cnt, srcs, v, lane);
  float p = 0.0f;
  if (lane < 32) {
    int cl = lane;
    float d = dinv[v];
    float4 bb = ((const float4*)bias)[cl];
    float4 wv = ((const float4*)Wl)[cl];
    float r0 = fmaxf(acc.x * d + bb.x, 0.0f);
    float r1 = fmaxf(acc.y * d + bb.y, 0.0f);
    float r2 = fmaxf(acc.z * d + bb.z, 0.0f);
    float r3 = fmaxf(acc.w * d + bb.w, 0.0f);
    p = r0 * wv.x + r1 * wv.y + r2 * wv.z + r3 * wv.w;
  }
  p += __shfl_down(p, 16, 64);
  p += __shfl_down(p, 8, 64);
  p += __shfl_down(p, 4, 64);
  p += __shfl_down(p, 2, 64);
  p += __shfl_down(p, 1, 64);
  if (lane == 0) {
    float z = p + bl[0];
    out[v] = 1.0f / (1.0f + expf(-z));
  }
}

// ---------------- launch ----------------

extern "C" void kernel_launch(void* const* d_in, const int* in_sizes, int n_in,
                              void* d_out, int out_size, void* d_ws, size_t ws_size,
                              hipStream_t stream) {
  const float* x  = (const float*)d_in[0];
  const int*   ei = (const int*)d_in[1];
  const float* W1 = (const float*)d_in[2];
  const float* b1 = (const float*)d_in[3];
  const float* W2 = (const float*)d_in[4];
  const float* b2 = (const float*)d_in[5];
  const float* Wl = (const float*)d_in[6];
  const float* bl = (const float*)d_in[7];
  float* out = (float*)d_out;

  int n  = in_sizes[0] / FDIM;   // 100000
  int nE = in_sizes[1] / 2;      // 3200000
  const int* row = ei;
  const int* col = ei + nE;
  int nb = (n + BKT_W - 1) >> BKT_BITS;   // 391

  // workspace carve (~53 MB); pairs aliases hb (hb first written after k_fine)
  unsigned char* s8 = (unsigned char*)d_ws;             // n*128 bytes (fp8)
  unsigned int* hb  = (unsigned int*)(s8 + (size_t)n * 128); // n*64 dwords (bf16x2)
  float* dinv  = (float*)(hb + (size_t)n * 64);         // n
  int*   cnt   = (int*)(dinv + n);                      // n
  int*   offs  = cnt + n;                               // n
  int*   srcs  = offs + n;                              // nE (byte offsets)
  int*   gbcnt = srcs + nE;                             // nb
  int*   gboff = gbcnt + nb;                            // nb+1
  int*   gcur  = gboff + nb + 1;                        // nb
  int*   pairs = (int*)hb;                              // nE packed (aliased)

  hipMemsetAsync(gbcnt, 0, (size_t)nb * sizeof(int), stream);
  k_bhist<<<256, 256, 0, stream>>>(col, gbcnt, nE, nb);
  k_bscan<<<1, 512, 0, stream>>>(gbcnt, gboff, gcur, nb, nE);
  int chunk = (nE + 255) / 256;   // 12500 <= BIN_CHUNK
  k_bin<<<256, 256, 0, stream>>>(row, col, gcur, pairs, nE, chunk, nb);
  k_fine<<<nb, 256, 0, stream>>>(pairs, gboff, srcs, offs, cnt, dinv, n);

  int gemm_grid = (n + 63) / 64;  // 64 rows per block (4 waves x 16 rows)
  int wave_grid = (n + 3) / 4;    // 4 waves / 256-thread block
  k_gemm_mfma_f<<<gemm_grid, 256, 0, stream>>>(x, W1, dinv, s8, n);
  k_agg_mid<<<wave_grid, 256, 0, stream>>>(s8, offs, cnt, srcs, dinv, b1, hb, n);
  k_gemm_mfma_b<<<gemm_grid, 256, 0, stream>>>(hb, W2, dinv, s8, n);
  k_agg_head<<<wave_grid, 256, 0, stream>>>(s8, offs, cnt, srcs, dinv, b2, Wl, bl, out, n);
}

// Round 13
// 367.342 us; speedup vs baseline: 1.0678x; 1.0678x over previous
//
#include <hip/hip_runtime.h>
#include <math.h>

#define FDIM 128
#define BKT_BITS 8                 // 256 nodes per bucket
#define BKT_W (1 << BKT_BITS)
#define BIN_CHUNK 12544            // max edges per k_bin block (256-block grid)

typedef short bf16x8 __attribute__((ext_vector_type(8)));
typedef float f32x4 __attribute__((ext_vector_type(4)));
typedef float f32x2 __attribute__((ext_vector_type(2)));

union ABu { bf16x8 v; unsigned int u[4]; };
union F4u { float4 f; float a[4]; };

__device__ inline unsigned int pack_bf16x2(float a, float b) {
  unsigned int ua = __float_as_uint(a);
  unsigned int ub = __float_as_uint(b);
  ua = (ua + 0x7fffu + ((ua >> 16) & 1u)) >> 16;   // RNE
  ub = (ub + 0x7fffu + ((ub >> 16) & 1u)) >> 16;
  return ua | (ub << 16);
}

// fp8 e4m3 (OCP on gfx950) helpers — hardware converts
__device__ inline unsigned char f32_to_fp8(float v) {
  return (unsigned char)(__builtin_amdgcn_cvt_pk_fp8_f32(v, v, 0, false) & 0xff);
}

// ---------------- CSR build: two-level binning ----------------

__global__ __launch_bounds__(256)
void k_bhist(const int* __restrict__ col, int* __restrict__ gbcnt, int nE, int nb) {
  __shared__ int lds[512];
  for (int i = threadIdx.x; i < 512; i += 256) lds[i] = 0;
  __syncthreads();
  int stride = gridDim.x * blockDim.x;
  for (int e = blockIdx.x * blockDim.x + threadIdx.x; e < nE; e += stride)
    atomicAdd(&lds[col[e] >> BKT_BITS], 1);
  __syncthreads();
  for (int b = threadIdx.x; b < nb; b += 256) {
    int c = lds[b];
    if (c) atomicAdd(&gbcnt[b], c);
  }
}

__global__ __launch_bounds__(512)
void k_bscan(const int* __restrict__ gbcnt, int* __restrict__ gboff,
             int* __restrict__ gcur, int nb, int nE) {
  __shared__ int lds[512];
  int t = threadIdx.x;
  lds[t] = (t < nb) ? gbcnt[t] : 0;
  __syncthreads();
  for (int off = 1; off < 512; off <<= 1) {
    int x = (t >= off) ? lds[t - off] : 0;
    __syncthreads();
    lds[t] += x;
    __syncthreads();
  }
  if (t < nb) {
    int excl = (t == 0) ? 0 : lds[t - 1];
    gboff[t] = excl;
    gcur[t] = excl;
  }
  if (t == 0) gboff[nb] = nE;
}

// level-1 scatter: packed (row | col_low<<24), bucket-contiguous.
__global__ __launch_bounds__(256)
void k_bin(const int* __restrict__ row, const int* __restrict__ col,
           int* __restrict__ gcur, int* __restrict__ pairs, int nE, int chunk, int nb) {
  __shared__ int bcnt[512];
  __shared__ int lcur[512];
  __shared__ int ecol[BIN_CHUNK];
  int e0 = blockIdx.x * chunk;
  int e1 = min(e0 + chunk, nE);
  int m = e1 - e0;
  for (int i = threadIdx.x; i < 512; i += 256) bcnt[i] = 0;
  for (int i = threadIdx.x; i < m; i += 256) ecol[i] = col[e0 + i];
  __syncthreads();
  for (int i = threadIdx.x; i < m; i += 256)
    atomicAdd(&bcnt[((unsigned)ecol[i]) >> BKT_BITS], 1);
  __syncthreads();
  for (int b = threadIdx.x; b < nb; b += 256) {
    int c = bcnt[b];
    lcur[b] = c ? atomicAdd(&gcur[b], c) : 0;
  }
  __syncthreads();
  for (int i = threadIdx.x; i < m; i += 256) {
    int c = ecol[i];
    int r = row[e0 + i];
    int p = atomicAdd(&lcur[((unsigned)c) >> BKT_BITS], 1);
    pairs[p] = r | ((c & (BKT_W - 1)) << 24);
  }
}

// fine pass: one block per bucket. cnt/offs/dinv + LDS-cursor scatter of rows.
// srcs is written as BYTE OFFSETS (row*128) for the fp8 gather.
__global__ __launch_bounds__(256)
void k_fine(const int* __restrict__ pairs, const int* __restrict__ gboff,
            int* __restrict__ srcs, int* __restrict__ offs, int* __restrict__ cnt,
            float* __restrict__ dinv, int n) {
  __shared__ int lcnt[256];
  __shared__ int lcur[256];
  int b = blockIdx.x;
  int t = threadIdx.x;
  int ebase = gboff[b];
  int eend = gboff[b + 1];
  lcnt[t] = 0;
  __syncthreads();
  for (int e = ebase + t; e < eend; e += 256)
    atomicAdd(&lcnt[((unsigned)pairs[e]) >> 24], 1);
  __syncthreads();
  int orig = lcnt[t];
  for (int off = 1; off < 256; off <<= 1) {
    int x = (t >= off) ? lcnt[t - off] : 0;
    __syncthreads();
    lcnt[t] += x;
    __syncthreads();
  }
  int excl = lcnt[t] - orig;
  int v = (b << BKT_BITS) + t;
  if (v < n) {
    offs[v] = ebase + excl;
    cnt[v] = orig;
    dinv[v] = rsqrtf((float)(orig + 1));  // +1 self loop
  }
  lcur[t] = ebase + excl;
  __syncthreads();
  for (int e = ebase + t; e < eend; e += 256) {
    int pr = pairs[e];
    int p = atomicAdd(&lcur[((unsigned)pr) >> 24], 1);
    srcs[p] = (pr & 0x00FFFFFF) << 7;   // byte offset of source row
  }
}

// ---------- MFMA GEMM: [n,128] x W[128,128], *dinv[row], fp8 out ----------
// W staged to LDS as W^T bf16, XOR-swizzled (unit ^= col&15 -> 2-way = free).
#define STAGE_WT()                                                          \
  {                                                                         \
    int c = threadIdx.x & 127;                                              \
    for (int kp = (threadIdx.x >> 7); kp < 64; kp += 2) {                   \
      float w0 = W[(kp * 2) * 128 + c];                                     \
      float w1 = W[(kp * 2 + 1) * 128 + c];                                 \
      int unit = kp >> 2, dw = kp & 3;                                      \
      wlds[c * 64 + ((unit ^ (c & 15)) << 2) + dw] = pack_bf16x2(w0, w1);   \
    }                                                                       \
  }                                                                         \
  __syncthreads();

#define GEMM_BODY()                                                         \
  int l = threadIdx.x & 63;                                                 \
  int grp = l >> 4, c15 = l & 15;                                           \
  int rbase = blockIdx.x * 64 + (threadIdx.x >> 6) * 16;                    \
  F4u dv;                                                                   \
  dv.f = *(const float4*)(dinv + rbase + grp * 4);                          \
  f32x4 acc[8];                                                             \
  _Pragma("unroll")                                                         \
  for (int nt = 0; nt < 8; ++nt) acc[nt] = (f32x4){0.f, 0.f, 0.f, 0.f};    \
  _Pragma("unroll")                                                         \
  for (int nt = 0; nt < 8; ++nt) {                                          \
    _Pragma("unroll")                                                       \
    for (int ks = 0; ks < 4; ++ks) {                                        \
      ABu b;                                                                \
      b.v = *(const bf16x8*)&wlds[(nt * 16 + c15) * 64 +                    \
                                  ((((ks << 2) + grp) ^ c15) << 2)];        \
      acc[nt] = __builtin_amdgcn_mfma_f32_16x16x32_bf16(a[ks].v, b.v,       \
                                                        acc[nt], 0, 0, 0);  \
    }                                                                       \
  }                                                                         \
  _Pragma("unroll")                                                         \
  for (int nt = 0; nt < 8; ++nt) {                                          \
    _Pragma("unroll")                                                       \
    for (int i = 0; i < 4; ++i) {                                           \
      int r = rbase + grp * 4 + i;                                          \
      if (r < n) {                                                          \
        float v = acc[nt][i] * dv.a[i];                                     \
        out[(size_t)r * 128 + nt * 16 + c15] = f32_to_fp8(v);               \
      }                                                                     \
    }                                                                       \
  }

__global__ __launch_bounds__(256)
void k_gemm_mfma_f(const float* __restrict__ in, const float* __restrict__ W,
                   const float* __restrict__ dinv, unsigned char* __restrict__ out,
                   int n) {
  __shared__ unsigned int wlds[128 * 64];
  STAGE_WT();
  {
    int l0 = threadIdx.x & 63;
    int row = blockIdx.x * 64 + (threadIdx.x >> 6) * 16 + (l0 & 15);
    int rowc = min(row, n - 1);
    int grp0 = l0 >> 4;
    const float4* xr = (const float4*)(in + (size_t)rowc * 128);
    ABu a[4];
#pragma unroll
    for (int ks = 0; ks < 4; ++ks) {
      float4 f0 = xr[ks * 8 + grp0 * 2];
      float4 f1 = xr[ks * 8 + grp0 * 2 + 1];
      a[ks].u[0] = pack_bf16x2(f0.x, f0.y);
      a[ks].u[1] = pack_bf16x2(f0.z, f0.w);
      a[ks].u[2] = pack_bf16x2(f1.x, f1.y);
      a[ks].u[3] = pack_bf16x2(f1.z, f1.w);
    }
    GEMM_BODY();
  }
}

__global__ __launch_bounds__(256)
void k_gemm_mfma_b(const unsigned int* __restrict__ in, const float* __restrict__ W,
                   const float* __restrict__ dinv, unsigned char* __restrict__ out,
                   int n) {
  __shared__ unsigned int wlds[128 * 64];
  STAGE_WT();
  {
    int l0 = threadIdx.x & 63;
    int row = blockIdx.x * 64 + (threadIdx.x >> 6) * 16 + (l0 & 15);
    int rowc = min(row, n - 1);
    int grp0 = l0 >> 4;
    const unsigned int* hr = in + (size_t)rowc * 64;
    ABu a[4];
#pragma unroll
    for (int ks = 0; ks < 4; ++ks)
      a[ks].v = *(const bf16x8*)&hr[ks * 16 + grp0 * 4];
    GEMM_BODY();
  }
}

// ------ gather core: wave/node, dword/lane, shfl-broadcast offsets, 8 rows/iter ------
// srcs holds pre-scaled byte offsets (row*128); coalesced 64-wide preload,
// register broadcast via shfl; half-wave hf gathers its own row.
__device__ inline float4 agg_core(const unsigned char* __restrict__ s8,
                                  const int* __restrict__ offs,
                                  const int* __restrict__ cnt,
                                  const int* __restrict__ srcs,
                                  int v, int lane) {
  int cl = lane & 31;
  int hf = lane >> 5;
  int co = cl * 4;               // byte offset of this lane's 4 fp8 cols
  float4 acc = make_float4(0.f, 0.f, 0.f, 0.f);
  if (lane < 32) {  // self contribution counted once
    unsigned int q = *(const unsigned int*)(s8 + (unsigned)(v * 128 + co));
    f32x2 lo = __builtin_amdgcn_cvt_pk_f32_fp8((int)q, false);
    f32x2 hi = __builtin_amdgcn_cvt_pk_f32_fp8((int)q, true);
    acc = make_float4(lo[0], lo[1], hi[0], hi[1]);
  }
  int beg = offs[v];
  int m = cnt[v];
  for (int base = 0; base < m; base += 64) {
    int take = m - base;
    if (take > 64) take = 64;
    int off = (lane < take) ? srcs[beg + base + lane] : 0;
    int it = 0;
    for (; it + 7 < take; it += 8) {
      int o0 = __shfl(off, it + hf, 64);
      int o1 = __shfl(off, it + 2 + hf, 64);
      int o2 = __shfl(off, it + 4 + hf, 64);
      int o3 = __shfl(off, it + 6 + hf, 64);
      unsigned int q0 = *(const unsigned int*)(s8 + (unsigned)(o0 + co));
      unsigned int q1 = *(const unsigned int*)(s8 + (unsigned)(o1 + co));
      unsigned int q2 = *(const unsigned int*)(s8 + (unsigned)(o2 + co));
      unsigned int q3 = *(const unsigned int*)(s8 + (unsigned)(o3 + co));
      f32x2 l0 = __builtin_amdgcn_cvt_pk_f32_fp8((int)q0, false);
      f32x2 h0 = __builtin_amdgcn_cvt_pk_f32_fp8((int)q0, true);
      f32x2 l1 = __builtin_amdgcn_cvt_pk_f32_fp8((int)q1, false);
      f32x2 h1 = __builtin_amdgcn_cvt_pk_f32_fp8((int)q1, true);
      f32x2 l2 = __builtin_amdgcn_cvt_pk_f32_fp8((int)q2, false);
      f32x2 h2 = __builtin_amdgcn_cvt_pk_f32_fp8((int)q2, true);
      f32x2 l3 = __builtin_amdgcn_cvt_pk_f32_fp8((int)q3, false);
      f32x2 h3 = __builtin_amdgcn_cvt_pk_f32_fp8((int)q3, true);
      acc.x += (l0[0] + l1[0]) + (l2[0] + l3[0]);
      acc.y += (l0[1] + l1[1]) + (l2[1] + l3[1]);
      acc.z += (h0[0] + h1[0]) + (h2[0] + h3[0]);
      acc.w += (h0[1] + h1[1]) + (h2[1] + h3[1]);
    }
    for (; it + 1 < take; it += 2) {
      int o = __shfl(off, it + hf, 64);
      unsigned int q = *(const unsigned int*)(s8 + (unsigned)(o + co));
      f32x2 lo = __builtin_amdgcn_cvt_pk_f32_fp8((int)q, false);
      f32x2 hi = __builtin_amdgcn_cvt_pk_f32_fp8((int)q, true);
      acc.x += lo[0]; acc.y += lo[1]; acc.z += hi[0]; acc.w += hi[1];
    }
    if (it < take) {  // odd tail: low half only
      int o = __shfl(off, it, 64);
      if (lane < 32) {
        unsigned int q = *(const unsigned int*)(s8 + (unsigned)(o + co));
        f32x2 lo = __builtin_amdgcn_cvt_pk_f32_fp8((int)q, false);
        f32x2 hi = __builtin_amdgcn_cvt_pk_f32_fp8((int)q, true);
        acc.x += lo[0]; acc.y += lo[1]; acc.z += hi[0]; acc.w += hi[1];
      }
    }
  }
  // combine the two half-wave partials
  acc.x += __shfl_xor(acc.x, 32, 64);
  acc.y += __shfl_xor(acc.y, 32, 64);
  acc.z += __shfl_xor(acc.z, 32, 64);
  acc.w += __shfl_xor(acc.w, 32, 64);
  return acc;
}

// layer-1 aggregate: h = relu(dinv*(...)+b), stored bf16 (coalesced reader)
__global__ __launch_bounds__(256)
void k_agg_mid(const unsigned char* __restrict__ s8, const int* __restrict__ offs,
               const int* __restrict__ cnt, const int* __restrict__ srcs,
               const float* __restrict__ dinv, const float* __restrict__ bias,
               unsigned int* __restrict__ hb, int n) {
  int v = (int)(((size_t)blockIdx.x * blockDim.x + threadIdx.x) >> 6);
  if (v >= n) return;
  int lane = threadIdx.x & 63;
  float4 acc = agg_core(s8, offs, cnt, srcs, v, lane);
  if (lane < 32) {
    int cl = lane;
    float d = dinv[v];
    float4 bb = ((const float4*)bias)[cl];
    float r0 = fmaxf(acc.x * d + bb.x, 0.0f);
    float r1 = fmaxf(acc.y * d + bb.y, 0.0f);
    float r2 = fmaxf(acc.z * d + bb.z, 0.0f);
    float r3 = fmaxf(acc.w * d + bb.w, 0.0f);
    uint2 pk;
    pk.x = pack_bf16x2(r0, r1);
    pk.y = pack_bf16x2(r2, r3);
    ((uint2*)hb)[(size_t)v * 32 + cl] = pk;
  }
}

// layer-2 aggregate fused with head: out = sigmoid(relu(...)@Wl + bl)
__global__ __launch_bounds__(256)
void k_agg_head(const unsigned char* __restrict__ s8, const int* __restrict__ offs,
                const int* __restrict__ cnt, const int* __restrict__ srcs,
                const float* __restrict__ dinv, const float* __restrict__ bias,
                const float* __restrict__ Wl, const float* __restrict__ bl,
                float* __restrict__ out, int n) {
  int v = (int)(((size_t)blockIdx.x * blockDim.x + threadIdx.x) >> 6);
  if (v >= n) return;
  int lane = threadIdx.x & 63;
  float4 acc = agg_core(s8, offs, cnt, srcs, v, lane);
  float p = 0.0f;
  if (lane < 32) {
    int cl = lane;
    float d = dinv[v];
    float4 bb = ((const float4*)bias)[cl];
    float4 wv = ((const float4*)Wl)[cl];
    float r0 = fmaxf(acc.x * d + bb.x, 0.0f);
    float r1 = fmaxf(acc.y * d + bb.y, 0.0f);
    float r2 = fmaxf(acc.z * d + bb.z, 0.0f);
    float r3 = fmaxf(acc.w * d + bb.w, 0.0f);
    p = r0 * wv.x + r1 * wv.y + r2 * wv.z + r3 * wv.w;
  }
  p += __shfl_down(p, 16, 64);
  p += __shfl_down(p, 8, 64);
  p += __shfl_down(p, 4, 64);
  p += __shfl_down(p, 2, 64);
  p += __shfl_down(p, 1, 64);
  if (lane == 0) {
    float z = p + bl[0];
    out[v] = 1.0f / (1.0f + expf(-z));
  }
}

// ---------------- launch ----------------

extern "C" void kernel_launch(void* const* d_in, const int* in_sizes, int n_in,
                              void* d_out, int out_size, void* d_ws, size_t ws_size,
                              hipStream_t stream) {
  const float* x  = (const float*)d_in[0];
  const int*   ei = (const int*)d_in[1];
  const float* W1 = (const float*)d_in[2];
  const float* b1 = (const float*)d_in[3];
  const float* W2 = (const float*)d_in[4];
  const float* b2 = (const float*)d_in[5];
  const float* Wl = (const float*)d_in[6];
  const float* bl = (const float*)d_in[7];
  float* out = (float*)d_out;

  int n  = in_sizes[0] / FDIM;   // 100000
  int nE = in_sizes[1] / 2;      // 3200000
  const int* row = ei;
  const int* col = ei + nE;
  int nb = (n + BKT_W - 1) >> BKT_BITS;   // 391

  // workspace carve (~53 MB); pairs aliases hb (hb first written after k_fine)
  unsigned char* s8 = (unsigned char*)d_ws;             // n*128 bytes (fp8)
  unsigned int* hb  = (unsigned int*)(s8 + (size_t)n * 128); // n*64 dwords (bf16x2)
  float* dinv  = (float*)(hb + (size_t)n * 64);         // n
  int*   cnt   = (int*)(dinv + n);                      // n
  int*   offs  = cnt + n;                               // n
  int*   srcs  = offs + n;                              // nE (byte offsets)
  int*   gbcnt = srcs + nE;                             // nb
  int*   gboff = gbcnt + nb;                            // nb+1
  int*   gcur  = gboff + nb + 1;                        // nb
  int*   pairs = (int*)hb;                              // nE packed (aliased)

  hipMemsetAsync(gbcnt, 0, (size_t)nb * sizeof(int), stream);
  k_bhist<<<256, 256, 0, stream>>>(col, gbcnt, nE, nb);
  k_bscan<<<1, 512, 0, stream>>>(gbcnt, gboff, gcur, nb, nE);
  int chunk = (nE + 255) / 256;   // 12500 <= BIN_CHUNK
  k_bin<<<256, 256, 0, stream>>>(row, col, gcur, pairs, nE, chunk, nb);
  k_fine<<<nb, 256, 0, stream>>>(pairs, gboff, srcs, offs, cnt, dinv, n);

  int gemm_grid = (n + 63) / 64;  // 64 rows per block (4 waves x 16 rows)
  int wave_grid = (n + 3) / 4;    // 4 waves / 256-thread block
  k_gemm_mfma_f<<<gemm_grid, 256, 0, stream>>>(x, W1, dinv, s8, n);
  k_agg_mid<<<wave_grid, 256, 0, stream>>>(s8, offs, cnt, srcs, dinv, b1, hb, n);
  k_gemm_mfma_b<<<gemm_grid, 256, 0, stream>>>(hb, W2, dinv, s8, n);
  k_agg_head<<<wave_grid, 256, 0, stream>>>(s8, offs, cnt, srcs, dinv, b2, Wl, bl, out, n);
}